// Round 10
// baseline (91.455 us; speedup 1.0000x reference)
//
#include <hip/hip_runtime.h>
#include <hip/hip_bf16.h>
#include <stdint.h>

// B=8, N=1024, D_IN=D_OUT=512, H=8, DH=64, SCALE=8
// Round 10: attn bias register double-buffer (hide L2-miss/L3 latency under a
// full tile body); gemm_o ported to global_load_lds staging (r9 qkv recipe).

typedef __attribute__((ext_vector_type(4))) float f32x4;
typedef __attribute__((ext_vector_type(8))) short s16x8;
typedef __attribute__((ext_vector_type(4))) unsigned short u16x4;
typedef __attribute__((ext_vector_type(8))) unsigned short u16x8;

union FragAB { s16x8 v; u16x4 h[2]; unsigned u[4]; };

#define LOG2E 1.44269504089f
#define QSCALE (0.125f * LOG2E)

__device__ __forceinline__ unsigned short f2b(float f) {
  unsigned u = __builtin_bit_cast(unsigned, f);
  u = (u + 0x7FFFu + ((u >> 16) & 1u)) >> 16;  // RNE
  return (unsigned short)u;
}
// D.lo = bf16(a), D.hi = bf16(b), RNE — identical values to f2b pairs.
__device__ __forceinline__ unsigned cvt_pk(float a, float b) {
  unsigned r;
  asm("v_cvt_pk_bf16_f32 %0, %1, %2" : "=v"(r) : "v"(a), "v"(b));
  return r;
}
// async global->LDS, 16B per lane; LDS dest = wave-uniform base + lane*16.
__device__ __forceinline__ void gl_lds16(const unsigned short* g, unsigned short* l) {
  __builtin_amdgcn_global_load_lds(
      (const __attribute__((address_space(1))) unsigned int*)(g),
      (__attribute__((address_space(3))) unsigned int*)(l), 16, 0, 0);
}

// ---------------- merged prep: x->bf16 (blocks 0..4095), W transpose (4096..4351)
__global__ __launch_bounds__(256) void prep_k(const float* __restrict__ x,
                                              unsigned short* __restrict__ xb,
                                              const float* __restrict__ W0,
                                              const float* __restrict__ W1,
                                              const float* __restrict__ W2,
                                              const float* __restrict__ W3,
                                              unsigned short* __restrict__ Wt) {
  __shared__ float ld[64][68];
  const int t = threadIdx.x;
  if (blockIdx.x < 4096) {
    int idx = blockIdx.x * 256 + t;
    f32x4 v = ((const f32x4*)x)[idx];
    u16x4 o;
#pragma unroll
    for (int j = 0; j < 4; j++) o[j] = f2b(v[j]);
    ((u16x4*)xb)[idx] = o;
    return;
  }
  const int bid2 = blockIdx.x - 4096;
  const int widx = bid2 >> 6;
  const int tile = bid2 & 63;
  const int trow = tile >> 3, tcol = tile & 7;
  const float* W = widx == 0 ? W0 : widx == 1 ? W1 : widx == 2 ? W2 : W3;
  const int r = t >> 2, cc = (t & 3) * 16;
  const float* src = W + (size_t)(trow * 64 + r) * 512 + tcol * 64 + cc;
#pragma unroll
  for (int u = 0; u < 4; u++)
    ((f32x4*)&ld[r][cc])[u] = ((const f32x4*)src)[u];
  __syncthreads();
  unsigned short* dst = Wt + ((size_t)widx << 18) + (size_t)(tcol * 64 + r) * 512 +
                        trow * 64 + cc;
#pragma unroll
  for (int u = 0; u < 4; u++) {
    u16x4 o;
#pragma unroll
    for (int e = 0; e < 4; e++) o[e] = f2b(ld[cc + u * 4 + e][r]);
    ((u16x4*)dst)[u] = o;
  }
}

// ---------------- fused QKV GEMM: global_load_lds staging, V^T epilogue ----------------
__global__ __launch_bounds__(256, 2) void gemm_qkv_k(const unsigned short* __restrict__ A,
                                                     const unsigned short* __restrict__ Bt,
                                                     const float* __restrict__ bq,
                                                     const float* __restrict__ bk,
                                                     const float* __restrict__ bv,
                                                     unsigned short* __restrict__ outp) {
  __shared__ unsigned short SM[2][2][128][32];  // [buf][A/B][row][k] linear, 32KB
  const int tid = threadIdx.x;
  const int lane = tid & 63;
  const int w = tid >> 6;
  const int wm = w >> 1, wn = w & 1;
  const int g = lane >> 4, c = lane & 15;
  const int bn0 = (blockIdx.x % 12) * 128;
  const int bm0 = (blockIdx.x / 12) * 128;

  f32x4 acc[4][4];
#pragma unroll
  for (int i = 0; i < 4; i++)
#pragma unroll
    for (int j = 0; j < 4; j++) acc[i][j] = f32x4{0.f, 0.f, 0.f, 0.f};

  auto stage = [&](int buf, int kt) {
#pragma unroll
    for (int j = 0; j < 2; j++) {
      const int qb = (j * 4 + w) * 64;
      const int chunk = qb + lane;
      const int row = chunk >> 2, slot = chunk & 3;
      gl_lds16(A + (size_t)(bm0 + row) * 512 + kt * 32 + slot * 8,
               &SM[buf][0][0][0] + qb * 8);
      gl_lds16(Bt + (size_t)(bn0 + row) * 512 + kt * 32 + slot * 8,
               &SM[buf][1][0][0] + qb * 8);
    }
  };

  stage(0, 0);
  asm volatile("s_waitcnt vmcnt(0)" ::: "memory");
  __syncthreads();

  for (int kt = 0; kt < 16; ++kt) {
    const int cb = kt & 1;
    if (kt < 15) stage(cb ^ 1, kt + 1);

    FragAB af[4], bf[4];
#pragma unroll
    for (int mi = 0; mi < 4; mi++) {
      const u16x4* p = (const u16x4*)&SM[cb][0][wm * 64 + mi * 16 + c][g * 8];
      af[mi].h[0] = p[0]; af[mi].h[1] = p[1];
    }
#pragma unroll
    for (int ni = 0; ni < 4; ni++) {
      const u16x4* p = (const u16x4*)&SM[cb][1][wn * 64 + ni * 16 + c][g * 8];
      bf[ni].h[0] = p[0]; bf[ni].h[1] = p[1];
    }
    __builtin_amdgcn_s_setprio(1);
#pragma unroll
    for (int mi = 0; mi < 4; mi++)
#pragma unroll
      for (int ni = 0; ni < 4; ni++)
        acc[mi][ni] = __builtin_amdgcn_mfma_f32_16x16x32_bf16(af[mi].v, bf[ni].v,
                                                              acc[mi][ni], 0, 0, 0);
    __builtin_amdgcn_s_setprio(0);

    if (kt < 15) {
      asm volatile("s_waitcnt vmcnt(0)" ::: "memory");
      __syncthreads();
    }
  }

  __syncthreads();  // all frag reads done; SM reusable as scratch

  const int qkv = (bn0 + wn * 64) >> 9;  // wave-uniform: 0=Q 1=K 2=V
  const float* bp = qkv == 0 ? bq : (qkv == 1 ? bk : bv);
  const float scale = qkv == 0 ? QSCALE : 1.0f;
  const int b = (bm0 + wm * 64) >> 10;
  const int nb = (bm0 + wm * 64) & 1023;

  if (qkv == 2) {
    unsigned short* T = &SM[0][0][0][0] + w * 2176;
    const int hh = ((bn0 + wn * 64) & 511) >> 6;
    unsigned short* dst = outp + ((size_t)2 << 22) + ((size_t)((b << 3) + hh) << 16) + nb;
#pragma unroll
    for (int r2 = 0; r2 < 2; r2++) {
#pragma unroll
      for (int ni2 = 0; ni2 < 2; ni2++) {
        const int ni = r2 * 2 + ni2;
        const int dloc = ni2 * 16 + c;
        const float bvv = bp[(bn0 + wn * 64 + ni * 16 + c) & 511];
#pragma unroll
        for (int mi = 0; mi < 4; mi++) {
          const int n = mi * 16 + g * 4;
          *(unsigned*)&T[dloc * 68 + n] =
              cvt_pk(acc[mi][ni][0] + bvv, acc[mi][ni][1] + bvv);
          *(unsigned*)&T[dloc * 68 + n + 2] =
              cvt_pk(acc[mi][ni][2] + bvv, acc[mi][ni][3] + bvv);
        }
      }
      asm volatile("s_waitcnt lgkmcnt(0)" ::: "memory");
#pragma unroll
      for (int r = 0; r < 8; r++) {
        const int dloc = r * 4 + g;
        const u16x4 v4 = *(const u16x4*)&T[dloc * 68 + c * 4];
        *(u16x4*)(dst + ((size_t)(r2 * 32 + dloc) << 10) + c * 4) = v4;
      }
      if (r2 == 0) asm volatile("s_waitcnt lgkmcnt(0)" ::: "memory");
    }
  } else {
#pragma unroll
    for (int mi = 0; mi < 4; mi++)
#pragma unroll
      for (int ni = 0; ni < 4; ni++) {
        const int c9 = (bn0 + wn * 64 + ni * 16 + c) & 511;
        const float bvv = bp[c9];
        const int hh = c9 >> 6, d = c9 & 63;
#pragma unroll
        for (int m = 0; m < 4; m++) {
          const int n = nb + mi * 16 + g * 4 + m;
          const float v = (acc[mi][ni][m] + bvv) * scale;
          outp[((size_t)qkv << 22) + ((size_t)((b << 3) + hh) << 16) +
               ((size_t)n << 6) + d] = f2b(v);
        }
      }
  }
}

// ---------------- output GEMM: 8 waves, global_load_lds staging ----------------
__global__ __launch_bounds__(512, 2) void gemm_o_k(const unsigned short* __restrict__ A,
                                                   const unsigned short* __restrict__ Bt,
                                                   const float* __restrict__ bias,
                                                   float* __restrict__ outp) {
  __shared__ unsigned short SM[2][2][128][32];
  const int tid = threadIdx.x;
  const int lane = tid & 63;
  const int w = tid >> 6;               // 0..7
  const int wm = w >> 1, wn = w & 1;    // 4x2 wave grid; wave tile 32x64
  const int g = lane >> 4, c = lane & 15;
  const int bn0 = (blockIdx.x & 3) * 128;
  const int bm0 = (blockIdx.x >> 2) * 128;

  f32x4 acc[2][4];
#pragma unroll
  for (int i = 0; i < 2; i++)
#pragma unroll
    for (int j = 0; j < 4; j++) acc[i][j] = f32x4{0.f, 0.f, 0.f, 0.f};

  auto stage = [&](int buf, int kt) {
    const int qb = w * 64;
    const int chunk = qb + lane;
    const int row = chunk >> 2, slot = chunk & 3;
    gl_lds16(A + (size_t)(bm0 + row) * 512 + kt * 32 + slot * 8,
             &SM[buf][0][0][0] + qb * 8);
    gl_lds16(Bt + (size_t)(bn0 + row) * 512 + kt * 32 + slot * 8,
             &SM[buf][1][0][0] + qb * 8);
  };

  stage(0, 0);
  asm volatile("s_waitcnt vmcnt(0)" ::: "memory");
  __syncthreads();

  for (int kt = 0; kt < 16; ++kt) {
    const int cb = kt & 1;
    if (kt < 15) stage(cb ^ 1, kt + 1);

    FragAB af[2], bf[4];
#pragma unroll
    for (int mi = 0; mi < 2; mi++) {
      const u16x4* p = (const u16x4*)&SM[cb][0][wm * 32 + mi * 16 + c][g * 8];
      af[mi].h[0] = p[0]; af[mi].h[1] = p[1];
    }
#pragma unroll
    for (int ni = 0; ni < 4; ni++) {
      const u16x4* p = (const u16x4*)&SM[cb][1][wn * 64 + ni * 16 + c][g * 8];
      bf[ni].h[0] = p[0]; bf[ni].h[1] = p[1];
    }
    __builtin_amdgcn_s_setprio(1);
#pragma unroll
    for (int mi = 0; mi < 2; mi++)
#pragma unroll
      for (int ni = 0; ni < 4; ni++)
        acc[mi][ni] = __builtin_amdgcn_mfma_f32_16x16x32_bf16(af[mi].v, bf[ni].v,
                                                              acc[mi][ni], 0, 0, 0);
    __builtin_amdgcn_s_setprio(0);

    if (kt < 15) {
      asm volatile("s_waitcnt vmcnt(0)" ::: "memory");
      __syncthreads();
    }
  }

#pragma unroll
  for (int mi = 0; mi < 2; mi++) {
#pragma unroll
    for (int ni = 0; ni < 4; ni++) {
      const int col = bn0 + wn * 64 + ni * 16 + c;
      const float bv = bias[col];
#pragma unroll
      for (int m = 0; m < 4; m++) {
        const int row = bm0 + wm * 32 + mi * 16 + g * 4 + m;
        outp[(size_t)row * 512 + col] = acc[mi][ni][m] + bv;
      }
    }
  }
}

// ---------------- flash attention: swapped-QK, bias reg double-buffer ----------------
__global__ __launch_bounds__(256, 2) void attn_k(const unsigned short* __restrict__ Qb,
                                                 const unsigned short* __restrict__ Kb,
                                                 const unsigned short* __restrict__ Vt,
                                                 const float* __restrict__ pos_bias,
                                                 unsigned short* __restrict__ ao) {
  __shared__ unsigned short Klds[2][64][68];
  __shared__ unsigned short Vtlds[2][64][68];  // [d][kv_row]
  __shared__ unsigned short Plds[4][32][68];   // [wave][q-local][kv]

  const int tid = threadIdx.x;
  const int lane = tid & 63;
  const int w = tid >> 6;
  const int g = lane >> 4, c = lane & 15;
  const int L = blockIdx.x;
  const int qt = L >> 6;
  const int bh = (L & 7) + 8 * ((L >> 3) & 7);  // XCD(L)=L%8 -> one head/XCD
  const int h = bh & 7;
  const size_t bhq = (size_t)bh << 16;
  const int q0 = qt * 128 + w * 32;

  FragAB aq[2][2];
#pragma unroll
  for (int mi = 0; mi < 2; mi++)
#pragma unroll
    for (int kk = 0; kk < 2; kk++) {
      const u16x4* p = (const u16x4*)(Qb + bhq + ((size_t)(q0 + mi * 16 + c) << 6) +
                                      kk * 32 + g * 8);
      aq[mi][kk].h[0] = p[0]; aq[mi][kk].h[1] = p[1];
    }

  f32x4 acco[2][4];
#pragma unroll
  for (int mi = 0; mi < 2; mi++)
#pragma unroll
    for (int nd = 0; nd < 4; nd++) acco[mi][nd] = f32x4{0.f, 0.f, 0.f, 0.f};
  float lsum[2] = {0.f, 0.f};

  const int srow = tid >> 2;
  const int scol = (tid & 3) * 16;
  const unsigned short* pK = Kb + bhq + ((size_t)srow << 6) + scol;
  const unsigned short* pV = Vt + bhq + ((size_t)srow << 10) + scol;

  u16x8 kr0, kr1, vr0, vr1;
  auto stageLoad = [&](int k0n) {
    const u16x8* a = (const u16x8*)(pK + ((size_t)k0n << 6));
    kr0 = a[0]; kr1 = a[1];
    const u16x8* bb = (const u16x8*)(pV + k0n);
    vr0 = bb[0]; vr1 = bb[1];
  };
  auto stageWrite = [&](int b) {
    *(u16x8*)&Klds[b][srow][scol] = kr0;
    *(u16x8*)&Klds[b][srow][scol + 8] = kr1;
    *(u16x8*)&Vtlds[b][srow][scol] = vr0;
    *(u16x8*)&Vtlds[b][srow][scol + 8] = vr1;
  };

  const float* pbB = pos_bias + ((size_t)h << 20) + ((size_t)(q0 + c) << 10) + 4 * g;

  // bias register double-buffer: tile 0 loaded up front
  f32x4 pbA[2][4], pbC[2][4];
#pragma unroll
  for (int mi = 0; mi < 2; mi++)
#pragma unroll
    for (int ni = 0; ni < 4; ni++)
      pbA[mi][ni] = *(const f32x4*)(pbB + (mi << 14) + 16 * ni);

  stageLoad(0);
  stageWrite(0);
  __syncthreads();

  auto body = [&](int kt, f32x4 (&pbu)[2][4], f32x4 (&pbn)[2][4]) {
    const int buf = kt & 1;
    const int k0 = kt << 6;
    if (kt < 15) {
      stageLoad(k0 + 64);
      // prefetch next tile's bias; consumed one full body later
#pragma unroll
      for (int mi = 0; mi < 2; mi++)
#pragma unroll
        for (int ni = 0; ni < 4; ni++)
          pbn[mi][ni] = *(const f32x4*)(pbB + (mi << 14) + k0 + 64 + 16 * ni);
    }

    // S^T = K @ Q^T
    FragAB bk[4][2];
#pragma unroll
    for (int ni = 0; ni < 4; ni++)
#pragma unroll
      for (int kk = 0; kk < 2; kk++) {
        const u16x4* p = (const u16x4*)&Klds[buf][ni * 16 + c][kk * 32 + g * 8];
        bk[ni][kk].h[0] = p[0]; bk[ni][kk].h[1] = p[1];
      }
    f32x4 sT[2][4];
    __builtin_amdgcn_s_setprio(1);
#pragma unroll
    for (int mi = 0; mi < 2; mi++)
#pragma unroll
      for (int ni = 0; ni < 4; ni++) {
        f32x4 s = f32x4{0.f, 0.f, 0.f, 0.f};
        s = __builtin_amdgcn_mfma_f32_16x16x32_bf16(bk[ni][0].v, aq[mi][0].v, s, 0, 0, 0);
        s = __builtin_amdgcn_mfma_f32_16x16x32_bf16(bk[ni][1].v, aq[mi][1].v, s, 0, 0, 0);
        sT[mi][ni] = s;
      }
    __builtin_amdgcn_s_setprio(0);

    // V-frag reads issued early: latency hides under softmax VALU
    FragAB vb2[4][2];
#pragma unroll
    for (int nd = 0; nd < 4; nd++)
#pragma unroll
      for (int kc = 0; kc < 2; kc++) {
        const u16x4* p = (const u16x4*)&Vtlds[buf][nd * 16 + c][kc * 32 + g * 8];
        vb2[nd][kc].h[0] = p[0]; vb2[nd][kc].h[1] = p[1];
      }

    // p = exp2(s + bias*log2e); pack via v_cvt_pk_bf16_f32
#pragma unroll
    for (int mi = 0; mi < 2; mi++)
#pragma unroll
      for (int ni = 0; ni < 4; ni++) {
        const float p0 = __builtin_amdgcn_exp2f(fmaf(pbu[mi][ni][0], LOG2E, sT[mi][ni][0]));
        const float p1 = __builtin_amdgcn_exp2f(fmaf(pbu[mi][ni][1], LOG2E, sT[mi][ni][1]));
        const float p2 = __builtin_amdgcn_exp2f(fmaf(pbu[mi][ni][2], LOG2E, sT[mi][ni][2]));
        const float p3 = __builtin_amdgcn_exp2f(fmaf(pbu[mi][ni][3], LOG2E, sT[mi][ni][3]));
        lsum[mi] += (p0 + p1) + (p2 + p3);
        uint2 two;
        two.x = cvt_pk(p0, p1);
        two.y = cvt_pk(p2, p3);
        *(uint2*)&Plds[w][mi * 16 + c][16 * ni + 4 * g] = two;
      }

    asm volatile("s_waitcnt lgkmcnt(0)" ::: "memory");

    // O += P @ V
    FragAB paf[2][2];
#pragma unroll
    for (int mi = 0; mi < 2; mi++)
#pragma unroll
      for (int kc = 0; kc < 2; kc++) {
        const u16x4* p = (const u16x4*)&Plds[w][mi * 16 + c][kc * 32 + g * 8];
        paf[mi][kc].h[0] = p[0]; paf[mi][kc].h[1] = p[1];
      }
    __builtin_amdgcn_s_setprio(1);
#pragma unroll
    for (int mi = 0; mi < 2; mi++)
#pragma unroll
      for (int nd = 0; nd < 4; nd++) {
        acco[mi][nd] = __builtin_amdgcn_mfma_f32_16x16x32_bf16(paf[mi][0].v, vb2[nd][0].v,
                                                               acco[mi][nd], 0, 0, 0);
        acco[mi][nd] = __builtin_amdgcn_mfma_f32_16x16x32_bf16(paf[mi][1].v, vb2[nd][1].v,
                                                               acco[mi][nd], 0, 0, 0);
      }
    __builtin_amdgcn_s_setprio(0);

    if (kt < 15) {
      stageWrite(buf ^ 1);
      __syncthreads();
    }
  };

  for (int kt2 = 0; kt2 < 16; kt2 += 2) {
    body(kt2, pbA, pbC);
    body(kt2 + 1, pbC, pbA);
  }

  const int b = bh >> 3;
#pragma unroll
  for (int mi = 0; mi < 2; mi++) {
    float l = lsum[mi];
    l += __shfl_xor(l, 16);
    l += __shfl_xor(l, 32);
    const float inv_c = 1.f / l;
#pragma unroll
    for (int m = 0; m < 4; m++) {
      const float invm = __shfl(inv_c, g * 4 + m);
      const int n = q0 + mi * 16 + g * 4 + m;
#pragma unroll
      for (int nd = 0; nd < 4; nd++) {
        ao[((size_t)(b * 1024 + n) << 9) + h * 64 + nd * 16 + c] =
            f2b(acco[mi][nd][m] * invm);
      }
    }
  }
}

// ---------------- launch ----------------
extern "C" void kernel_launch(void* const* d_in, const int* in_sizes, int n_in,
                              void* d_out, int out_size, void* d_ws, size_t ws_size,
                              hipStream_t stream) {
  (void)in_sizes; (void)n_in; (void)out_size; (void)ws_size;
  const float* x  = (const float*)d_in[0];
  const float* Wq = (const float*)d_in[1];
  const float* bq = (const float*)d_in[2];
  const float* Wk = (const float*)d_in[3];
  const float* bk = (const float*)d_in[4];
  const float* Wv = (const float*)d_in[5];
  const float* bv = (const float*)d_in[6];
  const float* Wo = (const float*)d_in[7];
  const float* bo = (const float*)d_in[8];
  const float* pbias = (const float*)d_in[9];

  char* p = (char*)d_ws;
  unsigned short* xb  = (unsigned short*)p; p += (size_t)8192 * 512 * 2;
  unsigned short* WT  = (unsigned short*)p; p += (size_t)4 * 512 * 512 * 2;
  unsigned short* Qb  = (unsigned short*)p; p += (size_t)3 * 64 * 1024 * 64 * 2;
  unsigned short* AO  = (unsigned short*)p;

  unsigned short* WoT = WT + (size_t)3 * 512 * 512;
  unsigned short* Kb  = Qb + (size_t)64 * 1024 * 64;
  unsigned short* Vb  = Kb + (size_t)64 * 1024 * 64;  // V^T slab [bh][d][n]

  prep_k<<<4352, 256, 0, stream>>>(x, xb, Wq, Wk, Wv, Wo, WT);
  gemm_qkv_k<<<768, 256, 0, stream>>>(xb, WT, bq, bk, bv, Qb);
  attn_k<<<512, 256, 0, stream>>>(Qb, Kb, Vb, pbias, AO);
  gemm_o_k<<<256, 512, 0, stream>>>(AO, WoT, bo, (float*)d_out);
}

// Round 11
// 85.636 us; speedup vs baseline: 1.0680x; 1.0680x over previous
//
#include <hip/hip_runtime.h>
#include <hip/hip_bf16.h>
#include <hip/hip_fp8.h>
#include <stdint.h>

// B=8, N=1024, D_IN=D_OUT=512, H=8, DH=64, SCALE=8
// Round 11: fp8(e4m3) pre-scaled pos_bias (4x fewer bias bytes; the r6-r10
// evidence shows attn is bias-bandwidth-bound on L2/L3). attn body = r9
// (no register double-buffer -> no spill). gemm_qkv/gemm_o as r10.

typedef __attribute__((ext_vector_type(4))) float f32x4;
typedef __attribute__((ext_vector_type(8))) short s16x8;
typedef __attribute__((ext_vector_type(4))) unsigned short u16x4;
typedef __attribute__((ext_vector_type(8))) unsigned short u16x8;

union FragAB { s16x8 v; u16x4 h[2]; unsigned u[4]; };

#define LOG2E 1.44269504089f
#define QSCALE (0.125f * LOG2E)
#define B8SCALE (64.0f * LOG2E)
#define B8INV 0.015625f

__device__ __forceinline__ unsigned short f2b(float f) {
  unsigned u = __builtin_bit_cast(unsigned, f);
  u = (u + 0x7FFFu + ((u >> 16) & 1u)) >> 16;  // RNE
  return (unsigned short)u;
}
__device__ __forceinline__ unsigned cvt_pk(float a, float b) {
  unsigned r;
  asm("v_cvt_pk_bf16_f32 %0, %1, %2" : "=v"(r) : "v"(a), "v"(b));
  return r;
}
__device__ __forceinline__ float f8tof(unsigned b) {
  __hip_fp8_e4m3 v;
  v.__x = (__hip_fp8_storage_t)b;
  return (float)v;
}
// async global->LDS, 16B per lane; LDS dest = wave-uniform base + lane*16.
__device__ __forceinline__ void gl_lds16(const unsigned short* g, unsigned short* l) {
  __builtin_amdgcn_global_load_lds(
      (const __attribute__((address_space(1))) unsigned int*)(g),
      (__attribute__((address_space(3))) unsigned int*)(l), 16, 0, 0);
}

// ---------------- merged prep ----------------
// blocks 0..4095: x->bf16 ; 4096..4351: W transpose ; 4352..6399: bias->fp8
__global__ __launch_bounds__(256) void prep_k(const float* __restrict__ x,
                                              unsigned short* __restrict__ xb,
                                              const float* __restrict__ W0,
                                              const float* __restrict__ W1,
                                              const float* __restrict__ W2,
                                              const float* __restrict__ W3,
                                              unsigned short* __restrict__ Wt,
                                              const float* __restrict__ pbias,
                                              unsigned char* __restrict__ pb8) {
  __shared__ float ld[64][68];
  const int t = threadIdx.x;
  if (blockIdx.x < 4096) {
    int idx = blockIdx.x * 256 + t;
    f32x4 v = ((const f32x4*)x)[idx];
    u16x4 o;
#pragma unroll
    for (int j = 0; j < 4; j++) o[j] = f2b(v[j]);
    ((u16x4*)xb)[idx] = o;
    return;
  }
  if (blockIdx.x >= 4352) {
    // pos_bias -> fp8 e4m3, pre-scaled by 64*log2e. 4096 elems/block.
    const int base = (blockIdx.x - 4352) * 4096 + t * 4;  // elem index
#pragma unroll
    for (int u = 0; u < 4; u++) {
      const int idx = base + u * 1024;
      f32x4 v = *(const f32x4*)(pbias + idx);
      unsigned wds = 0;
#pragma unroll
      for (int j = 0; j < 4; j++) {
        __hip_fp8_e4m3 f(v[j] * B8SCALE);
        wds |= (unsigned)f.__x << (8 * j);
      }
      *(unsigned*)(pb8 + idx) = wds;
    }
    return;
  }
  const int bid2 = blockIdx.x - 4096;
  const int widx = bid2 >> 6;
  const int tile = bid2 & 63;
  const int trow = tile >> 3, tcol = tile & 7;
  const float* W = widx == 0 ? W0 : widx == 1 ? W1 : widx == 2 ? W2 : W3;
  const int r = t >> 2, cc = (t & 3) * 16;
  const float* src = W + (size_t)(trow * 64 + r) * 512 + tcol * 64 + cc;
#pragma unroll
  for (int u = 0; u < 4; u++)
    ((f32x4*)&ld[r][cc])[u] = ((const f32x4*)src)[u];
  __syncthreads();
  unsigned short* dst = Wt + ((size_t)widx << 18) + (size_t)(tcol * 64 + r) * 512 +
                        trow * 64 + cc;
#pragma unroll
  for (int u = 0; u < 4; u++) {
    u16x4 o;
#pragma unroll
    for (int e = 0; e < 4; e++) o[e] = f2b(ld[cc + u * 4 + e][r]);
    ((u16x4*)dst)[u] = o;
  }
}

// ---------------- fused QKV GEMM: global_load_lds staging, V^T epilogue ----------------
__global__ __launch_bounds__(256, 2) void gemm_qkv_k(const unsigned short* __restrict__ A,
                                                     const unsigned short* __restrict__ Bt,
                                                     const float* __restrict__ bq,
                                                     const float* __restrict__ bk,
                                                     const float* __restrict__ bv,
                                                     unsigned short* __restrict__ outp) {
  __shared__ unsigned short SM[2][2][128][32];
  const int tid = threadIdx.x;
  const int lane = tid & 63;
  const int w = tid >> 6;
  const int wm = w >> 1, wn = w & 1;
  const int g = lane >> 4, c = lane & 15;
  const int bn0 = (blockIdx.x % 12) * 128;
  const int bm0 = (blockIdx.x / 12) * 128;

  f32x4 acc[4][4];
#pragma unroll
  for (int i = 0; i < 4; i++)
#pragma unroll
    for (int j = 0; j < 4; j++) acc[i][j] = f32x4{0.f, 0.f, 0.f, 0.f};

  auto stage = [&](int buf, int kt) {
#pragma unroll
    for (int j = 0; j < 2; j++) {
      const int qb = (j * 4 + w) * 64;
      const int chunk = qb + lane;
      const int row = chunk >> 2, slot = chunk & 3;
      gl_lds16(A + (size_t)(bm0 + row) * 512 + kt * 32 + slot * 8,
               &SM[buf][0][0][0] + qb * 8);
      gl_lds16(Bt + (size_t)(bn0 + row) * 512 + kt * 32 + slot * 8,
               &SM[buf][1][0][0] + qb * 8);
    }
  };

  stage(0, 0);
  asm volatile("s_waitcnt vmcnt(0)" ::: "memory");
  __syncthreads();

  for (int kt = 0; kt < 16; ++kt) {
    const int cb = kt & 1;
    if (kt < 15) stage(cb ^ 1, kt + 1);

    FragAB af[4], bf[4];
#pragma unroll
    for (int mi = 0; mi < 4; mi++) {
      const u16x4* p = (const u16x4*)&SM[cb][0][wm * 64 + mi * 16 + c][g * 8];
      af[mi].h[0] = p[0]; af[mi].h[1] = p[1];
    }
#pragma unroll
    for (int ni = 0; ni < 4; ni++) {
      const u16x4* p = (const u16x4*)&SM[cb][1][wn * 64 + ni * 16 + c][g * 8];
      bf[ni].h[0] = p[0]; bf[ni].h[1] = p[1];
    }
    __builtin_amdgcn_s_setprio(1);
#pragma unroll
    for (int mi = 0; mi < 4; mi++)
#pragma unroll
      for (int ni = 0; ni < 4; ni++)
        acc[mi][ni] = __builtin_amdgcn_mfma_f32_16x16x32_bf16(af[mi].v, bf[ni].v,
                                                              acc[mi][ni], 0, 0, 0);
    __builtin_amdgcn_s_setprio(0);

    if (kt < 15) {
      asm volatile("s_waitcnt vmcnt(0)" ::: "memory");
      __syncthreads();
    }
  }

  __syncthreads();  // SM reusable as scratch

  const int qkv = (bn0 + wn * 64) >> 9;
  const float* bp = qkv == 0 ? bq : (qkv == 1 ? bk : bv);
  const float scale = qkv == 0 ? QSCALE : 1.0f;
  const int b = (bm0 + wm * 64) >> 10;
  const int nb = (bm0 + wm * 64) & 1023;

  if (qkv == 2) {
    unsigned short* T = &SM[0][0][0][0] + w * 2176;
    const int hh = ((bn0 + wn * 64) & 511) >> 6;
    unsigned short* dst = outp + ((size_t)2 << 22) + ((size_t)((b << 3) + hh) << 16) + nb;
#pragma unroll
    for (int r2 = 0; r2 < 2; r2++) {
#pragma unroll
      for (int ni2 = 0; ni2 < 2; ni2++) {
        const int ni = r2 * 2 + ni2;
        const int dloc = ni2 * 16 + c;
        const float bvv = bp[(bn0 + wn * 64 + ni * 16 + c) & 511];
#pragma unroll
        for (int mi = 0; mi < 4; mi++) {
          const int n = mi * 16 + g * 4;
          *(unsigned*)&T[dloc * 68 + n] =
              cvt_pk(acc[mi][ni][0] + bvv, acc[mi][ni][1] + bvv);
          *(unsigned*)&T[dloc * 68 + n + 2] =
              cvt_pk(acc[mi][ni][2] + bvv, acc[mi][ni][3] + bvv);
        }
      }
      asm volatile("s_waitcnt lgkmcnt(0)" ::: "memory");
#pragma unroll
      for (int r = 0; r < 8; r++) {
        const int dloc = r * 4 + g;
        const u16x4 v4 = *(const u16x4*)&T[dloc * 68 + c * 4];
        *(u16x4*)(dst + ((size_t)(r2 * 32 + dloc) << 10) + c * 4) = v4;
      }
      if (r2 == 0) asm volatile("s_waitcnt lgkmcnt(0)" ::: "memory");
    }
  } else {
#pragma unroll
    for (int mi = 0; mi < 4; mi++)
#pragma unroll
      for (int ni = 0; ni < 4; ni++) {
        const int c9 = (bn0 + wn * 64 + ni * 16 + c) & 511;
        const float bvv = bp[c9];
        const int hh = c9 >> 6, d = c9 & 63;
#pragma unroll
        for (int m = 0; m < 4; m++) {
          const int n = nb + mi * 16 + g * 4 + m;
          const float v = (acc[mi][ni][m] + bvv) * scale;
          outp[((size_t)qkv << 22) + ((size_t)((b << 3) + hh) << 16) +
               ((size_t)n << 6) + d] = f2b(v);
        }
      }
  }
}

// ---------------- output GEMM: 8 waves, global_load_lds staging ----------------
__global__ __launch_bounds__(512, 2) void gemm_o_k(const unsigned short* __restrict__ A,
                                                   const unsigned short* __restrict__ Bt,
                                                   const float* __restrict__ bias,
                                                   float* __restrict__ outp) {
  __shared__ unsigned short SM[2][2][128][32];
  const int tid = threadIdx.x;
  const int lane = tid & 63;
  const int w = tid >> 6;
  const int wm = w >> 1, wn = w & 1;
  const int g = lane >> 4, c = lane & 15;
  const int bn0 = (blockIdx.x & 3) * 128;
  const int bm0 = (blockIdx.x >> 2) * 128;

  f32x4 acc[2][4];
#pragma unroll
  for (int i = 0; i < 2; i++)
#pragma unroll
    for (int j = 0; j < 4; j++) acc[i][j] = f32x4{0.f, 0.f, 0.f, 0.f};

  auto stage = [&](int buf, int kt) {
    const int qb = w * 64;
    const int chunk = qb + lane;
    const int row = chunk >> 2, slot = chunk & 3;
    gl_lds16(A + (size_t)(bm0 + row) * 512 + kt * 32 + slot * 8,
             &SM[buf][0][0][0] + qb * 8);
    gl_lds16(Bt + (size_t)(bn0 + row) * 512 + kt * 32 + slot * 8,
             &SM[buf][1][0][0] + qb * 8);
  };

  stage(0, 0);
  asm volatile("s_waitcnt vmcnt(0)" ::: "memory");
  __syncthreads();

  for (int kt = 0; kt < 16; ++kt) {
    const int cb = kt & 1;
    if (kt < 15) stage(cb ^ 1, kt + 1);

    FragAB af[2], bf[4];
#pragma unroll
    for (int mi = 0; mi < 2; mi++) {
      const u16x4* p = (const u16x4*)&SM[cb][0][wm * 32 + mi * 16 + c][g * 8];
      af[mi].h[0] = p[0]; af[mi].h[1] = p[1];
    }
#pragma unroll
    for (int ni = 0; ni < 4; ni++) {
      const u16x4* p = (const u16x4*)&SM[cb][1][wn * 64 + ni * 16 + c][g * 8];
      bf[ni].h[0] = p[0]; bf[ni].h[1] = p[1];
    }
    __builtin_amdgcn_s_setprio(1);
#pragma unroll
    for (int mi = 0; mi < 2; mi++)
#pragma unroll
      for (int ni = 0; ni < 4; ni++)
        acc[mi][ni] = __builtin_amdgcn_mfma_f32_16x16x32_bf16(af[mi].v, bf[ni].v,
                                                              acc[mi][ni], 0, 0, 0);
    __builtin_amdgcn_s_setprio(0);

    if (kt < 15) {
      asm volatile("s_waitcnt vmcnt(0)" ::: "memory");
      __syncthreads();
    }
  }

#pragma unroll
  for (int mi = 0; mi < 2; mi++) {
#pragma unroll
    for (int ni = 0; ni < 4; ni++) {
      const int col = bn0 + wn * 64 + ni * 16 + c;
      const float bv = bias[col];
#pragma unroll
      for (int m = 0; m < 4; m++) {
        const int row = bm0 + wm * 32 + mi * 16 + g * 4 + m;
        outp[(size_t)row * 512 + col] = acc[mi][ni][m] + bv;
      }
    }
  }
}

// ---------------- flash attention: swapped-QK, fp8 bias ----------------
__global__ __launch_bounds__(256, 2) void attn_k(const unsigned short* __restrict__ Qb,
                                                 const unsigned short* __restrict__ Kb,
                                                 const unsigned short* __restrict__ Vt,
                                                 const unsigned char* __restrict__ pb8,
                                                 unsigned short* __restrict__ ao) {
  __shared__ unsigned short Klds[2][64][68];
  __shared__ unsigned short Vtlds[2][64][68];  // [d][kv_row]
  __shared__ unsigned short Plds[4][32][68];   // [wave][q-local][kv]

  const int tid = threadIdx.x;
  const int lane = tid & 63;
  const int w = tid >> 6;
  const int g = lane >> 4, c = lane & 15;
  const int L = blockIdx.x;
  const int qt = L >> 6;
  const int bh = (L & 7) + 8 * ((L >> 3) & 7);  // XCD(L)=L%8 -> one head/XCD
  const int h = bh & 7;
  const size_t bhq = (size_t)bh << 16;
  const int q0 = qt * 128 + w * 32;

  FragAB aq[2][2];
#pragma unroll
  for (int mi = 0; mi < 2; mi++)
#pragma unroll
    for (int kk = 0; kk < 2; kk++) {
      const u16x4* p = (const u16x4*)(Qb + bhq + ((size_t)(q0 + mi * 16 + c) << 6) +
                                      kk * 32 + g * 8);
      aq[mi][kk].h[0] = p[0]; aq[mi][kk].h[1] = p[1];
    }

  f32x4 acco[2][4];
#pragma unroll
  for (int mi = 0; mi < 2; mi++)
#pragma unroll
    for (int nd = 0; nd < 4; nd++) acco[mi][nd] = f32x4{0.f, 0.f, 0.f, 0.f};
  float lsum[2] = {0.f, 0.f};

  const int srow = tid >> 2;
  const int scol = (tid & 3) * 16;
  const unsigned short* pK = Kb + bhq + ((size_t)srow << 6) + scol;
  const unsigned short* pV = Vt + bhq + ((size_t)srow << 10) + scol;

  u16x8 kr0, kr1, vr0, vr1;
  auto stageLoad = [&](int k0n) {
    const u16x8* a = (const u16x8*)(pK + ((size_t)k0n << 6));
    kr0 = a[0]; kr1 = a[1];
    const u16x8* bb = (const u16x8*)(pV + k0n);
    vr0 = bb[0]; vr1 = bb[1];
  };
  auto stageWrite = [&](int b) {
    *(u16x8*)&Klds[b][srow][scol] = kr0;
    *(u16x8*)&Klds[b][srow][scol + 8] = kr1;
    *(u16x8*)&Vtlds[b][srow][scol] = vr0;
    *(u16x8*)&Vtlds[b][srow][scol + 8] = vr1;
  };

  // fp8 bias: lane (c,g) needs pb8[h][q0+mi*16+c][k0+16ni+4g .. +3] = 1 dword
  const unsigned char* pbB = pb8 + ((size_t)h << 20) + ((size_t)(q0 + c) << 10) + 4 * g;

  stageLoad(0);
  stageWrite(0);
  __syncthreads();

  for (int kt = 0; kt < 16; ++kt) {
    const int buf = kt & 1;
    const int k0 = kt << 6;
    if (kt < 15) stageLoad(k0 + 64);

    // current tile's bias: 8 dword loads (4 fp8 each)
    unsigned pbw[2][4];
#pragma unroll
    for (int mi = 0; mi < 2; mi++)
#pragma unroll
      for (int ni = 0; ni < 4; ni++)
        pbw[mi][ni] = *(const unsigned*)(pbB + (mi << 14) + k0 + 16 * ni);

    // S^T = K @ Q^T
    FragAB bk[4][2];
#pragma unroll
    for (int ni = 0; ni < 4; ni++)
#pragma unroll
      for (int kk = 0; kk < 2; kk++) {
        const u16x4* p = (const u16x4*)&Klds[buf][ni * 16 + c][kk * 32 + g * 8];
        bk[ni][kk].h[0] = p[0]; bk[ni][kk].h[1] = p[1];
      }
    f32x4 sT[2][4];
    __builtin_amdgcn_s_setprio(1);
#pragma unroll
    for (int mi = 0; mi < 2; mi++)
#pragma unroll
      for (int ni = 0; ni < 4; ni++) {
        f32x4 s = f32x4{0.f, 0.f, 0.f, 0.f};
        s = __builtin_amdgcn_mfma_f32_16x16x32_bf16(bk[ni][0].v, aq[mi][0].v, s, 0, 0, 0);
        s = __builtin_amdgcn_mfma_f32_16x16x32_bf16(bk[ni][1].v, aq[mi][1].v, s, 0, 0, 0);
        sT[mi][ni] = s;
      }
    __builtin_amdgcn_s_setprio(0);

    // V-frag reads early (latency hides under softmax VALU)
    FragAB vb2[4][2];
#pragma unroll
    for (int nd = 0; nd < 4; nd++)
#pragma unroll
      for (int kc = 0; kc < 2; kc++) {
        const u16x4* p = (const u16x4*)&Vtlds[buf][nd * 16 + c][kc * 32 + g * 8];
        vb2[nd][kc].h[0] = p[0]; vb2[nd][kc].h[1] = p[1];
      }

    // p = exp2(s + b8/64); pack via v_cvt_pk_bf16_f32
#pragma unroll
    for (int mi = 0; mi < 2; mi++)
#pragma unroll
      for (int ni = 0; ni < 4; ni++) {
        const unsigned wd = pbw[mi][ni];
        const float p0 =
            __builtin_amdgcn_exp2f(fmaf(f8tof(wd & 255u), B8INV, sT[mi][ni][0]));
        const float p1 =
            __builtin_amdgcn_exp2f(fmaf(f8tof((wd >> 8) & 255u), B8INV, sT[mi][ni][1]));
        const float p2 =
            __builtin_amdgcn_exp2f(fmaf(f8tof((wd >> 16) & 255u), B8INV, sT[mi][ni][2]));
        const float p3 =
            __builtin_amdgcn_exp2f(fmaf(f8tof(wd >> 24), B8INV, sT[mi][ni][3]));
        lsum[mi] += (p0 + p1) + (p2 + p3);
        uint2 two;
        two.x = cvt_pk(p0, p1);
        two.y = cvt_pk(p2, p3);
        *(uint2*)&Plds[w][mi * 16 + c][16 * ni + 4 * g] = two;
      }

    asm volatile("s_waitcnt lgkmcnt(0)" ::: "memory");

    // O += P @ V
    FragAB paf[2][2];
#pragma unroll
    for (int mi = 0; mi < 2; mi++)
#pragma unroll
      for (int kc = 0; kc < 2; kc++) {
        const u16x4* p = (const u16x4*)&Plds[w][mi * 16 + c][kc * 32 + g * 8];
        paf[mi][kc].h[0] = p[0]; paf[mi][kc].h[1] = p[1];
      }
    __builtin_amdgcn_s_setprio(1);
#pragma unroll
    for (int mi = 0; mi < 2; mi++)
#pragma unroll
      for (int nd = 0; nd < 4; nd++) {
        acco[mi][nd] = __builtin_amdgcn_mfma_f32_16x16x32_bf16(paf[mi][0].v, vb2[nd][0].v,
                                                               acco[mi][nd], 0, 0, 0);
        acco[mi][nd] = __builtin_amdgcn_mfma_f32_16x16x32_bf16(paf[mi][1].v, vb2[nd][1].v,
                                                               acco[mi][nd], 0, 0, 0);
      }
    __builtin_amdgcn_s_setprio(0);

    if (kt < 15) {
      stageWrite(buf ^ 1);
      __syncthreads();
    }
  }

  const int b = bh >> 3;
#pragma unroll
  for (int mi = 0; mi < 2; mi++) {
    float l = lsum[mi];
    l += __shfl_xor(l, 16);
    l += __shfl_xor(l, 32);
    const float inv_c = 1.f / l;
#pragma unroll
    for (int m = 0; m < 4; m++) {
      const float invm = __shfl(inv_c, g * 4 + m);
      const int n = q0 + mi * 16 + g * 4 + m;
#pragma unroll
      for (int nd = 0; nd < 4; nd++) {
        ao[((size_t)(b * 1024 + n) << 9) + h * 64 + nd * 16 + c] =
            f2b(acco[mi][nd][m] * invm);
      }
    }
  }
}

// ---------------- launch ----------------
extern "C" void kernel_launch(void* const* d_in, const int* in_sizes, int n_in,
                              void* d_out, int out_size, void* d_ws, size_t ws_size,
                              hipStream_t stream) {
  (void)in_sizes; (void)n_in; (void)out_size; (void)ws_size;
  const float* x  = (const float*)d_in[0];
  const float* Wq = (const float*)d_in[1];
  const float* bq = (const float*)d_in[2];
  const float* Wk = (const float*)d_in[3];
  const float* bk = (const float*)d_in[4];
  const float* Wv = (const float*)d_in[5];
  const float* bv = (const float*)d_in[6];
  const float* Wo = (const float*)d_in[7];
  const float* bo = (const float*)d_in[8];
  const float* pbias = (const float*)d_in[9];

  char* p = (char*)d_ws;
  unsigned short* xb  = (unsigned short*)p; p += (size_t)8192 * 512 * 2;
  unsigned short* WT  = (unsigned short*)p; p += (size_t)4 * 512 * 512 * 2;
  unsigned short* Qb  = (unsigned short*)p; p += (size_t)3 * 64 * 1024 * 64 * 2;
  unsigned short* AO  = (unsigned short*)p; p += (size_t)8192 * 512 * 2;
  unsigned char*  PB8 = (unsigned char*)p;  // 8 MB fp8 bias

  unsigned short* WoT = WT + (size_t)3 * 512 * 512;
  unsigned short* Kb  = Qb + (size_t)64 * 1024 * 64;
  unsigned short* Vb  = Kb + (size_t)64 * 1024 * 64;  // V^T slab [bh][d][n]

  prep_k<<<6400, 256, 0, stream>>>(x, xb, Wq, Wk, Wv, Wo, WT, pbias, PB8);
  gemm_qkv_k<<<768, 256, 0, stream>>>(xb, WT, bq, bk, bv, Qb);
  attn_k<<<512, 256, 0, stream>>>(Qb, Kb, Vb, PB8, AO);
  gemm_o_k<<<256, 512, 0, stream>>>(AO, WoT, bo, (float*)d_out);
}

// Round 12
// 84.886 us; speedup vs baseline: 1.0774x; 1.0088x over previous
//
#include <hip/hip_runtime.h>
#include <hip/hip_bf16.h>
#include <stdint.h>

// B=8, N=1024, D_IN=D_OUT=512, H=8, DH=64, SCALE=8
// Round 12: native fp8 cvt (v_cvt_pk_f32_fp8 / v_cvt_pk_fp8_f32) replaces
// software-emulated __hip_fp8 casts (r11 showed +9pt VALUBusy from emulation);
// bias->fp8 conversion folded into the gemm_qkv launch (overlaps GEMM).

typedef __attribute__((ext_vector_type(2))) float f32x2;
typedef __attribute__((ext_vector_type(4))) float f32x4;
typedef __attribute__((ext_vector_type(8))) short s16x8;
typedef __attribute__((ext_vector_type(4))) unsigned short u16x4;
typedef __attribute__((ext_vector_type(8))) unsigned short u16x8;

union FragAB { s16x8 v; u16x4 h[2]; unsigned u[4]; };

#define LOG2E 1.44269504089f
#define QSCALE (0.125f * LOG2E)
#define B8SCALE (64.0f * LOG2E)
#define B8INV 0.015625f

__device__ __forceinline__ unsigned short f2b(float f) {
  unsigned u = __builtin_bit_cast(unsigned, f);
  u = (u + 0x7FFFu + ((u >> 16) & 1u)) >> 16;  // RNE
  return (unsigned short)u;
}
__device__ __forceinline__ unsigned cvt_pk(float a, float b) {
  unsigned r;
  asm("v_cvt_pk_bf16_f32 %0, %1, %2" : "=v"(r) : "v"(a), "v"(b));
  return r;
}
// native fp8 decode: bits[7:0] -> r[0], bits[15:8] -> r[1]
__device__ __forceinline__ f32x2 cvt2_f8(unsigned w) {
  f32x2 r;
  asm("v_cvt_pk_f32_fp8 %0, %1" : "=v"(r) : "v"(w));
  return r;
}
// native fp8 encode: (a,b) -> 2 fp8 in bits [15:0] of result
__device__ __forceinline__ unsigned enc2_f8(float a, float b) {
  unsigned r;
  asm("v_cvt_pk_fp8_f32 %0, %1, %2" : "=v"(r) : "v"(a), "v"(b));
  return r & 0xffffu;
}
// async global->LDS, 16B per lane; LDS dest = wave-uniform base + lane*16.
__device__ __forceinline__ void gl_lds16(const unsigned short* g, unsigned short* l) {
  __builtin_amdgcn_global_load_lds(
      (const __attribute__((address_space(1))) unsigned int*)(g),
      (__attribute__((address_space(3))) unsigned int*)(l), 16, 0, 0);
}

// ---------------- merged prep: x->bf16 (blocks 0..4095), W transpose (4096..4351)
__global__ __launch_bounds__(256) void prep_k(const float* __restrict__ x,
                                              unsigned short* __restrict__ xb,
                                              const float* __restrict__ W0,
                                              const float* __restrict__ W1,
                                              const float* __restrict__ W2,
                                              const float* __restrict__ W3,
                                              unsigned short* __restrict__ Wt) {
  __shared__ float ld[64][68];
  const int t = threadIdx.x;
  if (blockIdx.x < 4096) {
    int idx = blockIdx.x * 256 + t;
    f32x4 v = ((const f32x4*)x)[idx];
    u16x4 o;
#pragma unroll
    for (int j = 0; j < 4; j++) o[j] = f2b(v[j]);
    ((u16x4*)xb)[idx] = o;
    return;
  }
  const int bid2 = blockIdx.x - 4096;
  const int widx = bid2 >> 6;
  const int tile = bid2 & 63;
  const int trow = tile >> 3, tcol = tile & 7;
  const float* W = widx == 0 ? W0 : widx == 1 ? W1 : widx == 2 ? W2 : W3;
  const int r = t >> 2, cc = (t & 3) * 16;
  const float* src = W + (size_t)(trow * 64 + r) * 512 + tcol * 64 + cc;
#pragma unroll
  for (int u = 0; u < 4; u++)
    ((f32x4*)&ld[r][cc])[u] = ((const f32x4*)src)[u];
  __syncthreads();
  unsigned short* dst = Wt + ((size_t)widx << 18) + (size_t)(tcol * 64 + r) * 512 +
                        trow * 64 + cc;
#pragma unroll
  for (int u = 0; u < 4; u++) {
    u16x4 o;
#pragma unroll
    for (int e = 0; e < 4; e++) o[e] = f2b(ld[cc + u * 4 + e][r]);
    ((u16x4*)dst)[u] = o;
  }
}

// ---------------- fused QKV GEMM + bias->fp8 side blocks ----------------
// blocks 0..767: GEMM. blocks 768..2815: pos_bias -> fp8 (runs in GEMM shadow).
__global__ __launch_bounds__(256, 2) void gemm_qkv_k(const unsigned short* __restrict__ A,
                                                     const unsigned short* __restrict__ Bt,
                                                     const float* __restrict__ bq,
                                                     const float* __restrict__ bk,
                                                     const float* __restrict__ bv,
                                                     unsigned short* __restrict__ outp,
                                                     const float* __restrict__ pbias,
                                                     unsigned char* __restrict__ pb8) {
  __shared__ unsigned short SM[2][2][128][32];
  const int tid = threadIdx.x;

  if (blockIdx.x >= 768) {
    // bias conversion: 4096 elems/block, native pk encode
    const int base = (blockIdx.x - 768) * 4096 + tid * 4;
#pragma unroll
    for (int u = 0; u < 4; u++) {
      const int idx = base + u * 1024;
      f32x4 v = *(const f32x4*)(pbias + idx);
      const unsigned lo = enc2_f8(v[0] * B8SCALE, v[1] * B8SCALE);
      const unsigned hi = enc2_f8(v[2] * B8SCALE, v[3] * B8SCALE);
      *(unsigned*)(pb8 + idx) = lo | (hi << 16);
    }
    return;
  }

  const int lane = tid & 63;
  const int w = tid >> 6;
  const int wm = w >> 1, wn = w & 1;
  const int g = lane >> 4, c = lane & 15;
  const int bn0 = (blockIdx.x % 12) * 128;
  const int bm0 = (blockIdx.x / 12) * 128;

  f32x4 acc[4][4];
#pragma unroll
  for (int i = 0; i < 4; i++)
#pragma unroll
    for (int j = 0; j < 4; j++) acc[i][j] = f32x4{0.f, 0.f, 0.f, 0.f};

  auto stage = [&](int buf, int kt) {
#pragma unroll
    for (int j = 0; j < 2; j++) {
      const int qb = (j * 4 + w) * 64;
      const int chunk = qb + lane;
      const int row = chunk >> 2, slot = chunk & 3;
      gl_lds16(A + (size_t)(bm0 + row) * 512 + kt * 32 + slot * 8,
               &SM[buf][0][0][0] + qb * 8);
      gl_lds16(Bt + (size_t)(bn0 + row) * 512 + kt * 32 + slot * 8,
               &SM[buf][1][0][0] + qb * 8);
    }
  };

  stage(0, 0);
  asm volatile("s_waitcnt vmcnt(0)" ::: "memory");
  __syncthreads();

  for (int kt = 0; kt < 16; ++kt) {
    const int cb = kt & 1;
    if (kt < 15) stage(cb ^ 1, kt + 1);

    FragAB af[4], bf[4];
#pragma unroll
    for (int mi = 0; mi < 4; mi++) {
      const u16x4* p = (const u16x4*)&SM[cb][0][wm * 64 + mi * 16 + c][g * 8];
      af[mi].h[0] = p[0]; af[mi].h[1] = p[1];
    }
#pragma unroll
    for (int ni = 0; ni < 4; ni++) {
      const u16x4* p = (const u16x4*)&SM[cb][1][wn * 64 + ni * 16 + c][g * 8];
      bf[ni].h[0] = p[0]; bf[ni].h[1] = p[1];
    }
    __builtin_amdgcn_s_setprio(1);
#pragma unroll
    for (int mi = 0; mi < 4; mi++)
#pragma unroll
      for (int ni = 0; ni < 4; ni++)
        acc[mi][ni] = __builtin_amdgcn_mfma_f32_16x16x32_bf16(af[mi].v, bf[ni].v,
                                                              acc[mi][ni], 0, 0, 0);
    __builtin_amdgcn_s_setprio(0);

    if (kt < 15) {
      asm volatile("s_waitcnt vmcnt(0)" ::: "memory");
      __syncthreads();
    }
  }

  __syncthreads();  // SM reusable as scratch

  const int qkv = (bn0 + wn * 64) >> 9;
  const float* bp = qkv == 0 ? bq : (qkv == 1 ? bk : bv);
  const float scale = qkv == 0 ? QSCALE : 1.0f;
  const int b = (bm0 + wm * 64) >> 10;
  const int nb = (bm0 + wm * 64) & 1023;

  if (qkv == 2) {
    unsigned short* T = &SM[0][0][0][0] + w * 2176;
    const int hh = ((bn0 + wn * 64) & 511) >> 6;
    unsigned short* dst = outp + ((size_t)2 << 22) + ((size_t)((b << 3) + hh) << 16) + nb;
#pragma unroll
    for (int r2 = 0; r2 < 2; r2++) {
#pragma unroll
      for (int ni2 = 0; ni2 < 2; ni2++) {
        const int ni = r2 * 2 + ni2;
        const int dloc = ni2 * 16 + c;
        const float bvv = bp[(bn0 + wn * 64 + ni * 16 + c) & 511];
#pragma unroll
        for (int mi = 0; mi < 4; mi++) {
          const int n = mi * 16 + g * 4;
          *(unsigned*)&T[dloc * 68 + n] =
              cvt_pk(acc[mi][ni][0] + bvv, acc[mi][ni][1] + bvv);
          *(unsigned*)&T[dloc * 68 + n + 2] =
              cvt_pk(acc[mi][ni][2] + bvv, acc[mi][ni][3] + bvv);
        }
      }
      asm volatile("s_waitcnt lgkmcnt(0)" ::: "memory");
#pragma unroll
      for (int r = 0; r < 8; r++) {
        const int dloc = r * 4 + g;
        const u16x4 v4 = *(const u16x4*)&T[dloc * 68 + c * 4];
        *(u16x4*)(dst + ((size_t)(r2 * 32 + dloc) << 10) + c * 4) = v4;
      }
      if (r2 == 0) asm volatile("s_waitcnt lgkmcnt(0)" ::: "memory");
    }
  } else {
#pragma unroll
    for (int mi = 0; mi < 4; mi++)
#pragma unroll
      for (int ni = 0; ni < 4; ni++) {
        const int c9 = (bn0 + wn * 64 + ni * 16 + c) & 511;
        const float bvv = bp[c9];
        const int hh = c9 >> 6, d = c9 & 63;
#pragma unroll
        for (int m = 0; m < 4; m++) {
          const int n = nb + mi * 16 + g * 4 + m;
          const float v = (acc[mi][ni][m] + bvv) * scale;
          outp[((size_t)qkv << 22) + ((size_t)((b << 3) + hh) << 16) +
               ((size_t)n << 6) + d] = f2b(v);
        }
      }
  }
}

// ---------------- output GEMM: 8 waves, global_load_lds staging ----------------
__global__ __launch_bounds__(512, 2) void gemm_o_k(const unsigned short* __restrict__ A,
                                                   const unsigned short* __restrict__ Bt,
                                                   const float* __restrict__ bias,
                                                   float* __restrict__ outp) {
  __shared__ unsigned short SM[2][2][128][32];
  const int tid = threadIdx.x;
  const int lane = tid & 63;
  const int w = tid >> 6;
  const int wm = w >> 1, wn = w & 1;
  const int g = lane >> 4, c = lane & 15;
  const int bn0 = (blockIdx.x & 3) * 128;
  const int bm0 = (blockIdx.x >> 2) * 128;

  f32x4 acc[2][4];
#pragma unroll
  for (int i = 0; i < 2; i++)
#pragma unroll
    for (int j = 0; j < 4; j++) acc[i][j] = f32x4{0.f, 0.f, 0.f, 0.f};

  auto stage = [&](int buf, int kt) {
    const int qb = w * 64;
    const int chunk = qb + lane;
    const int row = chunk >> 2, slot = chunk & 3;
    gl_lds16(A + (size_t)(bm0 + row) * 512 + kt * 32 + slot * 8,
             &SM[buf][0][0][0] + qb * 8);
    gl_lds16(Bt + (size_t)(bn0 + row) * 512 + kt * 32 + slot * 8,
             &SM[buf][1][0][0] + qb * 8);
  };

  stage(0, 0);
  asm volatile("s_waitcnt vmcnt(0)" ::: "memory");
  __syncthreads();

  for (int kt = 0; kt < 16; ++kt) {
    const int cb = kt & 1;
    if (kt < 15) stage(cb ^ 1, kt + 1);

    FragAB af[2], bf[4];
#pragma unroll
    for (int mi = 0; mi < 2; mi++) {
      const u16x4* p = (const u16x4*)&SM[cb][0][wm * 32 + mi * 16 + c][g * 8];
      af[mi].h[0] = p[0]; af[mi].h[1] = p[1];
    }
#pragma unroll
    for (int ni = 0; ni < 4; ni++) {
      const u16x4* p = (const u16x4*)&SM[cb][1][wn * 64 + ni * 16 + c][g * 8];
      bf[ni].h[0] = p[0]; bf[ni].h[1] = p[1];
    }
    __builtin_amdgcn_s_setprio(1);
#pragma unroll
    for (int mi = 0; mi < 2; mi++)
#pragma unroll
      for (int ni = 0; ni < 4; ni++)
        acc[mi][ni] = __builtin_amdgcn_mfma_f32_16x16x32_bf16(af[mi].v, bf[ni].v,
                                                              acc[mi][ni], 0, 0, 0);
    __builtin_amdgcn_s_setprio(0);

    if (kt < 15) {
      asm volatile("s_waitcnt vmcnt(0)" ::: "memory");
      __syncthreads();
    }
  }

#pragma unroll
  for (int mi = 0; mi < 2; mi++) {
#pragma unroll
    for (int ni = 0; ni < 4; ni++) {
      const int col = bn0 + wn * 64 + ni * 16 + c;
      const float bv = bias[col];
#pragma unroll
      for (int m = 0; m < 4; m++) {
        const int row = bm0 + wm * 32 + mi * 16 + g * 4 + m;
        outp[(size_t)row * 512 + col] = acc[mi][ni][m] + bv;
      }
    }
  }
}

// ---------------- flash attention: swapped-QK, fp8 bias (native cvt) ----------------
__global__ __launch_bounds__(256, 2) void attn_k(const unsigned short* __restrict__ Qb,
                                                 const unsigned short* __restrict__ Kb,
                                                 const unsigned short* __restrict__ Vt,
                                                 const unsigned char* __restrict__ pb8,
                                                 unsigned short* __restrict__ ao) {
  __shared__ unsigned short Klds[2][64][68];
  __shared__ unsigned short Vtlds[2][64][68];  // [d][kv_row]
  __shared__ unsigned short Plds[4][32][68];   // [wave][q-local][kv]

  const int tid = threadIdx.x;
  const int lane = tid & 63;
  const int w = tid >> 6;
  const int g = lane >> 4, c = lane & 15;
  const int L = blockIdx.x;
  const int qt = L >> 6;
  const int bh = (L & 7) + 8 * ((L >> 3) & 7);  // XCD(L)=L%8 -> one head/XCD
  const int h = bh & 7;
  const size_t bhq = (size_t)bh << 16;
  const int q0 = qt * 128 + w * 32;

  FragAB aq[2][2];
#pragma unroll
  for (int mi = 0; mi < 2; mi++)
#pragma unroll
    for (int kk = 0; kk < 2; kk++) {
      const u16x4* p = (const u16x4*)(Qb + bhq + ((size_t)(q0 + mi * 16 + c) << 6) +
                                      kk * 32 + g * 8);
      aq[mi][kk].h[0] = p[0]; aq[mi][kk].h[1] = p[1];
    }

  f32x4 acco[2][4];
#pragma unroll
  for (int mi = 0; mi < 2; mi++)
#pragma unroll
    for (int nd = 0; nd < 4; nd++) acco[mi][nd] = f32x4{0.f, 0.f, 0.f, 0.f};
  float lsum[2] = {0.f, 0.f};

  const int srow = tid >> 2;
  const int scol = (tid & 3) * 16;
  const unsigned short* pK = Kb + bhq + ((size_t)srow << 6) + scol;
  const unsigned short* pV = Vt + bhq + ((size_t)srow << 10) + scol;

  u16x8 kr0, kr1, vr0, vr1;
  auto stageLoad = [&](int k0n) {
    const u16x8* a = (const u16x8*)(pK + ((size_t)k0n << 6));
    kr0 = a[0]; kr1 = a[1];
    const u16x8* bb = (const u16x8*)(pV + k0n);
    vr0 = bb[0]; vr1 = bb[1];
  };
  auto stageWrite = [&](int b) {
    *(u16x8*)&Klds[b][srow][scol] = kr0;
    *(u16x8*)&Klds[b][srow][scol + 8] = kr1;
    *(u16x8*)&Vtlds[b][srow][scol] = vr0;
    *(u16x8*)&Vtlds[b][srow][scol + 8] = vr1;
  };

  const unsigned char* pbB = pb8 + ((size_t)h << 20) + ((size_t)(q0 + c) << 10) + 4 * g;

  stageLoad(0);
  stageWrite(0);
  __syncthreads();

  for (int kt = 0; kt < 16; ++kt) {
    const int buf = kt & 1;
    const int k0 = kt << 6;
    if (kt < 15) stageLoad(k0 + 64);

    // current tile's bias: 8 dword loads (4 fp8 each)
    unsigned pbw[2][4];
#pragma unroll
    for (int mi = 0; mi < 2; mi++)
#pragma unroll
      for (int ni = 0; ni < 4; ni++)
        pbw[mi][ni] = *(const unsigned*)(pbB + (mi << 14) + k0 + 16 * ni);

    // S^T = K @ Q^T
    FragAB bk[4][2];
#pragma unroll
    for (int ni = 0; ni < 4; ni++)
#pragma unroll
      for (int kk = 0; kk < 2; kk++) {
        const u16x4* p = (const u16x4*)&Klds[buf][ni * 16 + c][kk * 32 + g * 8];
        bk[ni][kk].h[0] = p[0]; bk[ni][kk].h[1] = p[1];
      }
    f32x4 sT[2][4];
    __builtin_amdgcn_s_setprio(1);
#pragma unroll
    for (int mi = 0; mi < 2; mi++)
#pragma unroll
      for (int ni = 0; ni < 4; ni++) {
        f32x4 s = f32x4{0.f, 0.f, 0.f, 0.f};
        s = __builtin_amdgcn_mfma_f32_16x16x32_bf16(bk[ni][0].v, aq[mi][0].v, s, 0, 0, 0);
        s = __builtin_amdgcn_mfma_f32_16x16x32_bf16(bk[ni][1].v, aq[mi][1].v, s, 0, 0, 0);
        sT[mi][ni] = s;
      }
    __builtin_amdgcn_s_setprio(0);

    // V-frag reads early (latency hides under softmax VALU)
    FragAB vb2[4][2];
#pragma unroll
    for (int nd = 0; nd < 4; nd++)
#pragma unroll
      for (int kc = 0; kc < 2; kc++) {
        const u16x4* p = (const u16x4*)&Vtlds[buf][nd * 16 + c][kc * 32 + g * 8];
        vb2[nd][kc].h[0] = p[0]; vb2[nd][kc].h[1] = p[1];
      }

    // p = exp2(s + b8/64); native pk fp8 decode; pack via v_cvt_pk_bf16_f32
#pragma unroll
    for (int mi = 0; mi < 2; mi++)
#pragma unroll
      for (int ni = 0; ni < 4; ni++) {
        const unsigned wd = pbw[mi][ni];
        const f32x2 blo = cvt2_f8(wd);
        const f32x2 bhi = cvt2_f8(wd >> 16);
        const float p0 = __builtin_amdgcn_exp2f(fmaf(blo[0], B8INV, sT[mi][ni][0]));
        const float p1 = __builtin_amdgcn_exp2f(fmaf(blo[1], B8INV, sT[mi][ni][1]));
        const float p2 = __builtin_amdgcn_exp2f(fmaf(bhi[0], B8INV, sT[mi][ni][2]));
        const float p3 = __builtin_amdgcn_exp2f(fmaf(bhi[1], B8INV, sT[mi][ni][3]));
        lsum[mi] += (p0 + p1) + (p2 + p3);
        uint2 two;
        two.x = cvt_pk(p0, p1);
        two.y = cvt_pk(p2, p3);
        *(uint2*)&Plds[w][mi * 16 + c][16 * ni + 4 * g] = two;
      }

    asm volatile("s_waitcnt lgkmcnt(0)" ::: "memory");

    // O += P @ V
    FragAB paf[2][2];
#pragma unroll
    for (int mi = 0; mi < 2; mi++)
#pragma unroll
      for (int kc = 0; kc < 2; kc++) {
        const u16x4* p = (const u16x4*)&Plds[w][mi * 16 + c][kc * 32 + g * 8];
        paf[mi][kc].h[0] = p[0]; paf[mi][kc].h[1] = p[1];
      }
    __builtin_amdgcn_s_setprio(1);
#pragma unroll
    for (int mi = 0; mi < 2; mi++)
#pragma unroll
      for (int nd = 0; nd < 4; nd++) {
        acco[mi][nd] = __builtin_amdgcn_mfma_f32_16x16x32_bf16(paf[mi][0].v, vb2[nd][0].v,
                                                               acco[mi][nd], 0, 0, 0);
        acco[mi][nd] = __builtin_amdgcn_mfma_f32_16x16x32_bf16(paf[mi][1].v, vb2[nd][1].v,
                                                               acco[mi][nd], 0, 0, 0);
      }
    __builtin_amdgcn_s_setprio(0);

    if (kt < 15) {
      stageWrite(buf ^ 1);
      __syncthreads();
    }
  }

  const int b = bh >> 3;
#pragma unroll
  for (int mi = 0; mi < 2; mi++) {
    float l = lsum[mi];
    l += __shfl_xor(l, 16);
    l += __shfl_xor(l, 32);
    const float inv_c = 1.f / l;
#pragma unroll
    for (int m = 0; m < 4; m++) {
      const float invm = __shfl(inv_c, g * 4 + m);
      const int n = q0 + mi * 16 + g * 4 + m;
#pragma unroll
      for (int nd = 0; nd < 4; nd++) {
        ao[((size_t)(b * 1024 + n) << 9) + h * 64 + nd * 16 + c] =
            f2b(acco[mi][nd][m] * invm);
      }
    }
  }
}

// ---------------- launch ----------------
extern "C" void kernel_launch(void* const* d_in, const int* in_sizes, int n_in,
                              void* d_out, int out_size, void* d_ws, size_t ws_size,
                              hipStream_t stream) {
  (void)in_sizes; (void)n_in; (void)out_size; (void)ws_size;
  const float* x  = (const float*)d_in[0];
  const float* Wq = (const float*)d_in[1];
  const float* bq = (const float*)d_in[2];
  const float* Wk = (const float*)d_in[3];
  const float* bk = (const float*)d_in[4];
  const float* Wv = (const float*)d_in[5];
  const float* bv = (const float*)d_in[6];
  const float* Wo = (const float*)d_in[7];
  const float* bo = (const float*)d_in[8];
  const float* pbias = (const float*)d_in[9];

  char* p = (char*)d_ws;
  unsigned short* xb  = (unsigned short*)p; p += (size_t)8192 * 512 * 2;
  unsigned short* WT  = (unsigned short*)p; p += (size_t)4 * 512 * 512 * 2;
  unsigned short* Qb  = (unsigned short*)p; p += (size_t)3 * 64 * 1024 * 64 * 2;
  unsigned short* AO  = (unsigned short*)p; p += (size_t)8192 * 512 * 2;
  unsigned char*  PB8 = (unsigned char*)p;  // 8 MB fp8 bias

  unsigned short* WoT = WT + (size_t)3 * 512 * 512;
  unsigned short* Kb  = Qb + (size_t)64 * 1024 * 64;
  unsigned short* Vb  = Kb + (size_t)64 * 1024 * 64;  // V^T slab [bh][d][n]

  prep_k<<<4352, 256, 0, stream>>>(x, xb, Wq, Wk, Wv, Wo, WT);
  gemm_qkv_k<<<2816, 256, 0, stream>>>(xb, WT, bq, bk, bv, Qb, pbias, PB8);
  attn_k<<<512, 256, 0, stream>>>(Qb, Kb, Vb, PB8, AO);
  gemm_o_k<<<256, 512, 0, stream>>>(AO, WoT, bo, (float*)d_out);
}